// Round 17
// baseline (534.027 us; speedup 1.0000x reference)
//
#include <hip/hip_runtime.h>
#include <hip/hip_bf16.h>
#include <stdint.h>

#define B_Q   1024
#define C_K   262144
#define D_DIM 512
#define V_DIM 512
#define K_TOP 8
#define BM 128
#define BN 128
#define NT (C_K/BN)    /* 2048 nt-tiles */
#define TPB 32         /* nt-tiles per persistent block (grid 512) */
#define CAP 2048       /* candidate list capacity per query (E[n]~293) */
#define QS 8.0f        /* per-side fp8 pre-scale */
#define TAU_S 8.64f    /* 64 * 0.135 (z=3.05); rescore window 64 -> 13-sigma margin */
#define RWIN 64        /* exact-rescore window */
#define SC1 0x7F7F7F7F /* e8m0 scale bytes = 127 -> 2^0 = 1.0 (exact) */

typedef float f32x4  __attribute__((ext_vector_type(4)));
typedef float f32x16 __attribute__((ext_vector_type(16)));
typedef int   i32x8  __attribute__((ext_vector_type(8)));
typedef __attribute__((address_space(3))) unsigned char lds_uchar;
typedef __attribute__((address_space(1))) const unsigned char gbl_uchar;

// Block = one 32-row group (rt): L2-normalize + fp8 e4m3 + FRAGMENT-PACK.
// Frag (rt,kt) = 2KB at (rt*8+kt)*2048; lane l of MFMA reads l*16 (k 0..15)
// and 1024+l*16 (k 16..31), l = row + 32*(khalf). Thread (r=tid>>3, c=tid&7)
// covers k [c*64, c*64+64): byte pos for jl=0..7 (j = c*8+jl, same algebra as
// the R15/R16-passing formula): kt=c, h=(jl>>2)&1, sub=(jl>>1)&1, byte=(jl&1)*8.
// Scattered 8B writes go to LDS (cheap); global write = coalesced 16B/thread.
// Two-pass norm: sum-squares -> 8-lane shfl_xor reduce -> re-read (L1-hot).
// Block 0 zeroes candidate counters (when cnt != nullptr).
__global__ __launch_bounds__(256) void pack_rows(const float* __restrict__ in,
                                                 uint8_t* __restrict__ outp,
                                                 int* cnt, int ncnt){
  if (cnt != nullptr && blockIdx.x == 0){
    for (int i = threadIdx.x; i < ncnt; i += 256) cnt[i] = 0;
  }
  __shared__ __align__(16) unsigned char stg[16384];
  const int tid = threadIdx.x;
  const int r = tid >> 3;              // local row 0..31
  const int c = tid & 7;               // kt chunk 0..7
  const int rt = blockIdx.x;
  const size_t row = (size_t)rt*32 + r;
  const float4* src = (const float4*)(in + row*D_DIM + c*64);

  float ss = 0.f;
  #pragma unroll
  for (int i=0;i<16;i++){
    float4 x = src[i];
    ss += x.x*x.x + x.y*x.y + x.z*x.z + x.w*x.w;
  }
  ss += __shfl_xor(ss, 1); ss += __shfl_xor(ss, 2); ss += __shfl_xor(ss, 4);
  const float rn = QS / fmaxf(sqrtf(ss), 1e-12f);

  #pragma unroll
  for (int jl=0; jl<8; jl++){
    float4 a = src[jl*2], b = src[jl*2+1];
    int w0 = __builtin_amdgcn_cvt_pk_fp8_f32(a.x*rn, a.y*rn, 0,  false);
    w0     = __builtin_amdgcn_cvt_pk_fp8_f32(a.z*rn, a.w*rn, w0, true);
    int w1 = __builtin_amdgcn_cvt_pk_fp8_f32(b.x*rn, b.y*rn, 0,  false);
    w1     = __builtin_amdgcn_cvt_pk_fp8_f32(b.z*rn, b.w*rn, w1, true);
    unsigned off = (unsigned)c*2048u + ((jl>>1)&1)*1024u
                 + (unsigned)(r + 32*((jl>>2)&1))*16u + (jl&1)*8u;
    *(uint2*)(stg + off) = make_uint2((unsigned)w0, (unsigned)w1);
  }
  __syncthreads();
  uint4* g = (uint4*)(outp + (size_t)rt*16384u);
  const uint4* s4 = (const uint4*)stg;
  #pragma unroll
  for (int p=0; p<4; p++) g[tid + p*256] = s4[tid + p*256];
}

// PERSISTENT 128x128 fp8 GEMM, BARRIER-FREE K-loop (scores scaled by 64):
// A (query slab, 64KB frag-packed) STATIC in LDS — loaded once, read-only.
// B fragments stream from global with AFFINE addressing (no pointer chain,
// no tail guard — clamp index) and a 3-DEEP static prefetch rotation
// (b0<-b1<-b2<-load(st+3), 24 VGPR) => ~240cy cover >= L2 latency; flat
// 256-step loop unrolled x8 (epilogue under compile-time (st&7)==7).
// NO barriers / LDS writes / waitcnt after prologue — pure dataflow.
// R15 LESSON: no min-waves launch_bounds (forced 128-reg cap spilled acc).
// Epilogue by reference, per nt-tile threshold + rare atomic append.
__global__ __launch_bounds__(512) void gemm_topk(const uint8_t* __restrict__ qp,
                                                 const uint8_t* __restrict__ kp,
                                                 int* __restrict__ cnt,
                                                 float2* __restrict__ cand){
  extern __shared__ __align__(16) unsigned char alds[];   // 65536 bytes

  const int tid  = threadIdx.x;
  const int lane = tid & 63;
  const int w    = tid >> 6;           // 0..7
  const int wm = w >> 2, wn = w & 3;   // 2 x 4 wave grid: 128 rows x 128 cols

  const unsigned bid = blockIdx.x;     // 0..511
  const int xcd  = bid & 7;
  const int s    = bid >> 3;           // 0..63
  const int mt   = s & 7;              // 8 m-tiles
  const int nt0  = xcd*256 + (s >> 3)*TPB;   // group walks nt0..nt0+31

  // prologue: copy A slab (frags rt=mt*4..+4 x kt=0..8 = 64KB contiguous)
  #pragma unroll
  for (int i=0; i<8; i++)
    __builtin_amdgcn_global_load_lds(
        (gbl_uchar*)(qp + (size_t)mt*65536u + tid*16 + i*8192),
        (lds_uchar*)(alds + tid*16 + i*8192), 16, 0, 0);
  __syncthreads();                      // the ONLY block-wide sync

  f32x16 acc0 = {0}, acc1 = {0};
  union frag8 { uint4 q[2]; i32x8 v; };

  // B fragment stream, affine: step st -> bb + (st>>3)*65536 + (st&7)*2048
  const uint8_t* bb = kp + ((size_t)(nt0*4 + wn)*8)*2048 + (unsigned)lane*16u;
  #define BADDR(s_) (bb + (size_t)((s_)>>3)*65536u + (unsigned)(((s_)&7)*2048u))

  uint4 b0a = *(const uint4*)(BADDR(0)), b0b = *(const uint4*)(BADDR(0)+1024);
  uint4 b1a = *(const uint4*)(BADDR(1)), b1b = *(const uint4*)(BADDR(1)+1024);
  uint4 b2a = *(const uint4*)(BADDR(2)), b2b = *(const uint4*)(BADDR(2)+1024);

  const unsigned aoffA = (unsigned)(wm*16)*2048u + (unsigned)lane*16u; // mh=0 base

  // epilogue helper: by-reference (no f32x16 copy — R15 register lesson)
  #define EPILOG(accR_, mh_) do{                                                \
    const int rbase = mt*BM + wm*64 + (mh_)*32 + 4*(lane>>5);                    \
    _Pragma("unroll")                                                            \
    for (int qd=0; qd<4; qd++){                                                  \
      float v0=(accR_)[qd*4+0], v1=(accR_)[qd*4+1];                              \
      float v2=(accR_)[qd*4+2], v3=(accR_)[qd*4+3];                              \
      float mx = fmaxf(fmaxf(v0,v1), fmaxf(v2,v3));                              \
      if (mx > TAU_S){                                                           \
        _Pragma("unroll")                                                        \
        for (int jj=0; jj<4; jj++){                                              \
          float v = (accR_)[qd*4+jj];                                            \
          if (v > TAU_S){                                                        \
            int rowg = rbase + jj + 8*qd;                                        \
            int pos = atomicAdd(cnt + rowg, 1);                                  \
            if (pos < CAP)                                                       \
              cand[(size_t)rowg*CAP + pos] = make_float2(v, __int_as_float(colg)); \
          }                                                                      \
        }                                                                        \
      }                                                                          \
    }                                                                            \
  }while(0)

  #pragma unroll 8
  for (int st=0; st<TPB*8; st++){
    // A fragments from static LDS (conflict-free: lane*16 sequential)
    frag8 fa0, fa1, fb;
    const unsigned ao = aoffA + (unsigned)(st&7)*2048u;
    fa0.q[0] = *(const uint4*)(alds + ao);
    fa0.q[1] = *(const uint4*)(alds + ao + 1024u);
    fa1.q[0] = *(const uint4*)(alds + ao + 16384u);
    fa1.q[1] = *(const uint4*)(alds + ao + 16384u + 1024u);
    fb.q[0] = b0a; fb.q[1] = b0b;
    __builtin_amdgcn_s_setprio(1);
    acc0 = __builtin_amdgcn_mfma_scale_f32_32x32x64_f8f6f4(
               fa0.v, fb.v, acc0, 0, 0, 0, SC1, 0, SC1);
    acc1 = __builtin_amdgcn_mfma_scale_f32_32x32x64_f8f6f4(
               fa1.v, fb.v, acc1, 0, 0, 0, SC1, 0, SC1);
    __builtin_amdgcn_s_setprio(0);
    // rotate 3-deep prefetch (static renaming under unroll)
    b0a = b1a; b0b = b1b;
    b1a = b2a; b1b = b2b;
    const int sn = (st+3 < TPB*8) ? st+3 : TPB*8-1;   // clamp: in-bounds, unused
    b2a = *(const uint4*)(BADDR(sn));
    b2b = *(const uint4*)(BADDR(sn) + 1024);

    if ((st&7) == 7){
      // ---- per-nt-tile epilogue: threshold filter + rare atomic append ----
      const int ntc  = nt0 + (st>>3);
      const int colg = ntc*BN + wn*32 + (lane&31);
      EPILOG(acc0, 0);
      EPILOG(acc1, 1);
      acc0 = (f32x16){0}; acc1 = (f32x16){0};   // reset for next nt-tile
    }
  }
  #undef EPILOG
  #undef BADDR
}

// One block per query: exact rank-select top-64 from candidate list ->
// exact fp64 rescore -> exact top-8 (ties: lower index) -> outputs.
__global__ __launch_bounds__(256) void merge_rescore(const int* __restrict__ cnt,
                                                     const float2* __restrict__ cand,
                                                     const float* __restrict__ q,
                                                     const float* __restrict__ keys,
                                                     const float* __restrict__ values,
                                                     float* __restrict__ out){
  const int qi = blockIdx.x, tid = threadIdx.x;
  const int lane = tid & 63, w = tid >> 6;
  __shared__ __align__(16) float qrow[D_DIM];
  __shared__ __align__(16) float2 ent[CAP];
  __shared__ int    widx[RWIN];
  __shared__ double dsc[RWIN];
  __shared__ double wq[4];
  __shared__ int    fidx[8];
  __shared__ double fsc[8];

  // stage q row + fp64 ||q||^2
  float2 qv = ((const float2*)(q + (size_t)qi*D_DIM))[tid];
  qrow[tid*2] = qv.x; qrow[tid*2+1] = qv.y;
  double pq = (double)qv.x*qv.x + (double)qv.y*qv.y;
  #pragma unroll
  for (int off=32; off>0; off>>=1) pq += __shfl_xor(pq, off);
  if (lane == 0) wq[w] = pq;

  const int n = min(cnt[qi], CAP);
  for (int i = tid; i < n; i += 256) ent[i] = cand[(size_t)qi*CAP + i];
  if (tid < RWIN) widx[tid] = -1;
  __syncthreads();
  double qq = wq[0]+wq[1]+wq[2]+wq[3];

  // exact rank-select: rank under (score desc, col asc); ranks are unique.
  for (int e = tid; e < n; e += 256){
    float se = ent[e].x; int ce = __float_as_int(ent[e].y);
    int rank = 0;
    for (int jx = 0; jx < n; jx++){
      float sj = ent[jx].x; int cj = __float_as_int(ent[jx].y);
      rank += (sj > se) || (sj == se && cj < ce);
    }
    if (rank < RWIN) widx[rank] = ce;
  }
  __syncthreads();

  // exact fp64 rescore: 4 threads per candidate (64 x 4 = 256)
  const int g = tid >> 2, sub = tid & 3;
  const int ki = widx[g];
  const int kis = (ki < 0) ? 0 : ki;
  const float4* kr4 = (const float4*)(keys + (size_t)kis*D_DIM);
  const float4* qr4 = (const float4*)qrow;
  double da = 0.0, dk = 0.0;
  for (int i=0;i<32;i++){
    float4 kv  = kr4[sub*32+i];
    float4 qv4 = qr4[sub*32+i];
    da += (double)qv4.x*kv.x + (double)qv4.y*kv.y + (double)qv4.z*kv.z + (double)qv4.w*kv.w;
    dk += (double)kv.x*kv.x + (double)kv.y*kv.y + (double)kv.z*kv.z + (double)kv.w*kv.w;
  }
  da += __shfl_down(da, 2, 4); da += __shfl_down(da, 1, 4);
  dk += __shfl_down(dk, 2, 4); dk += __shfl_down(dk, 1, 4);
  if (sub == 0){
    double nq = fmax(sqrt(qq), 1e-12);
    double nk = fmax(sqrt(dk), 1e-12);
    dsc[g] = (ki < 0) ? -1e300 : da/(nq*nk);
  }
  __syncthreads();

  if (tid == 0){
    for (int s=0; s<8; s++){
      double bs = -1e301; int bi = 0; int bx = 0x7fffffff;
      for (int c=0; c<RWIN; c++){
        double v = dsc[c]; int ix = widx[c];
        if (v > bs || (v == bs && ix >= 0 && ix < bx)){ bs = v; bi = c; bx = ix; }
      }
      fsc[s] = bs; fidx[s] = (bx == 0x7fffffff) ? 0 : bx;
      dsc[bi] = -1e302;   // remove
    }
  }
  __syncthreads();

  float* out_sc  = out + (size_t)B_Q*K_TOP*V_DIM;
  float* out_idx = out_sc + (size_t)B_Q*K_TOP;
  if (tid < 8){
    out_sc [qi*K_TOP + tid] = (float)fsc[tid];
    out_idx[qi*K_TOP + tid] = (float)fidx[tid];
  }
  #pragma unroll
  for (int s=0; s<8; s++){
    const float2* vr = (const float2*)(values + (size_t)fidx[s]*V_DIM);
    float2* orow = (float2*)(out + ((size_t)qi*K_TOP + s)*V_DIM);
    orow[tid] = vr[tid];
  }
}

extern "C" void kernel_launch(void* const* d_in, const int* in_sizes, int n_in,
                              void* d_out, int out_size, void* d_ws, size_t ws_size,
                              hipStream_t stream){
  const float* q      = (const float*)d_in[0];
  const float* keys   = (const float*)d_in[1];
  const float* values = (const float*)d_in[2];
  unsigned char* ws = (unsigned char*)d_ws;
  uint8_t* qp = (uint8_t*)ws;                                   // 512 KB (fp8 frag-packed)
  uint8_t* kp = qp + (size_t)B_Q*D_DIM;                         // 128 MB (fp8 frag-packed)
  int*    cnt  = (int*)(ws + (size_t)(B_Q + C_K)*D_DIM);        // 4 KB
  float2* cand = (float2*)(ws + (size_t)(B_Q + C_K)*D_DIM + 8192); // 16 MB
  float* out = (float*)d_out;

  hipFuncSetAttribute((const void*)gemm_topk,
                      hipFuncAttributeMaxDynamicSharedMemorySize, 65536);

  pack_rows<<<dim3(B_Q/32), dim3(256), 0, stream>>>(q, qp, cnt, B_Q);
  pack_rows<<<dim3(C_K/32), dim3(256), 0, stream>>>(keys, kp, nullptr, 0);
  gemm_topk<<<dim3(512), dim3(512), 65536, stream>>>(qp, kp, cnt, cand);
  merge_rescore<<<dim3(B_Q), dim3(256), 0, stream>>>(cnt, cand, q, keys, values, out);
}

// Round 18
// 428.473 us; speedup vs baseline: 1.2463x; 1.2463x over previous
//
#include <hip/hip_runtime.h>
#include <hip/hip_bf16.h>
#include <stdint.h>

#define B_Q   1024
#define C_K   262144
#define D_DIM 512
#define V_DIM 512
#define K_TOP 8
#define BM 128
#define BN 128
#define NT (C_K/BN)    /* 2048 nt-tiles */
#define TPB 32         /* nt-tiles per persistent block (grid 512) */
#define CAP 2048       /* candidate list capacity per query (E[n]~293) */
#define QS 8.0f        /* per-side fp8 pre-scale */
#define TAU_S 8.64f    /* 64 * 0.135 (z=3.05); rescore window 64 -> 13-sigma margin */
#define RWIN 64        /* exact-rescore window */
#define SC1 0x7F7F7F7F /* e8m0 scale bytes = 127 -> 2^0 = 1.0 (exact) */

typedef float f32x4  __attribute__((ext_vector_type(4)));
typedef float f32x16 __attribute__((ext_vector_type(16)));
typedef int   i32x8  __attribute__((ext_vector_type(8)));
typedef __attribute__((address_space(3))) unsigned char lds_uchar;
typedef __attribute__((address_space(1))) const unsigned char gbl_uchar;

// Block = one 32-row frag-group (rt). 8 passes of the R16-proven wave-per-row
// pipeline (SINGLE read pass): wave w handles row r = p*4+w; lane j reads
// floats [j*8, j*8+8) coalesced; 64-lane shfl_xor norm; cvt to fp8; 8B store
// into 16KB LDS frag image with the BYTE-IDENTICAL R15/R16 algebra
// (kt=j>>3, h=(j>>2)&1, sub=(j>>1)&1, unit=(r+32h), byte=(j&1)*8). Then one
// coalesced 16B/thread flush (image is kt-major => identity copy to the rt's
// 16KB global span — flush layout proven in R17). Coalesced writes without
// R17's second read pass. Block 0 zeroes candidate counters (cnt != nullptr).
__global__ __launch_bounds__(256) void pack_rows(const float* __restrict__ in,
                                                 uint8_t* __restrict__ outp,
                                                 int* cnt, int ncnt){
  if (cnt != nullptr && blockIdx.x == 0){
    for (int i = threadIdx.x; i < ncnt; i += 256) cnt[i] = 0;
  }
  __shared__ __align__(16) unsigned char stg[16384];
  const int tid  = threadIdx.x;
  const int w    = tid >> 6;
  const int lane = tid & 63;
  const int rt   = blockIdx.x;
  const int kt = lane >> 3, h = (lane >> 2) & 1, sub = (lane >> 1) & 1;
  const unsigned obase = (unsigned)kt*2048u + (unsigned)sub*1024u + (lane & 1)*8u;

  #pragma unroll
  for (int p=0; p<8; p++){
    const int r = p*4 + w;             // local row 0..31
    const float4* r4 = (const float4*)(in + ((size_t)rt*32 + r)*D_DIM);
    float4 a = r4[lane*2], b = r4[lane*2+1];
    float ss = a.x*a.x+a.y*a.y+a.z*a.z+a.w*a.w
             + b.x*b.x+b.y*b.y+b.z*b.z+b.w*b.w;
    #pragma unroll
    for (int off=32; off>0; off>>=1) ss += __shfl_xor(ss, off);
    float rn = QS / fmaxf(sqrtf(ss), 1e-12f);
    int w0 = __builtin_amdgcn_cvt_pk_fp8_f32(a.x*rn, a.y*rn, 0,  false);
    w0     = __builtin_amdgcn_cvt_pk_fp8_f32(a.z*rn, a.w*rn, w0, true);
    int w1 = __builtin_amdgcn_cvt_pk_fp8_f32(b.x*rn, b.y*rn, 0,  false);
    w1     = __builtin_amdgcn_cvt_pk_fp8_f32(b.z*rn, b.w*rn, w1, true);
    *(uint2*)(stg + obase + (unsigned)(r + 32*h)*16u) =
        make_uint2((unsigned)w0, (unsigned)w1);
  }
  __syncthreads();
  uint4* g = (uint4*)(outp + (size_t)rt*16384u);
  const uint4* s4 = (const uint4*)stg;
  #pragma unroll
  for (int p=0; p<4; p++) g[tid + p*256] = s4[tid + p*256];
}

// PERSISTENT 128x128 fp8 GEMM, BARRIER-FREE K-loop (scores scaled by 64):
// A (query slab, 64KB frag-packed) STATIC in LDS — loaded once, read-only.
// B fragments stream from global (frag-packed => 2 coalesced dwordx4/wave;
// keys 128MB fit L3, 2MB walk-windows L2-hot, 8 mt-blocks share each window).
// Per wave-step: 4 conflict-free ds_read_b128 + 2 global loads (1-step
// prefetch) + 2 MX-scaled MFMA (scale=1.0 => exact fp8 products). NO
// barriers / LDS writes / waitcnt after prologue — pure dataflow.
// R15/R17 LESSON: no min-waves launch_bounds, no extra prefetch depth —
// register pressure past 128 drops to 1 block/CU or spills. R16 verbatim.
// Epilogue by REFERENCE (no f32x16 copy), per nt-tile threshold+append.
__global__ __launch_bounds__(512) void gemm_topk(const uint8_t* __restrict__ qp,
                                                 const uint8_t* __restrict__ kp,
                                                 int* __restrict__ cnt,
                                                 float2* __restrict__ cand){
  extern __shared__ __align__(16) unsigned char alds[];   // 65536 bytes

  const int tid  = threadIdx.x;
  const int lane = tid & 63;
  const int w    = tid >> 6;           // 0..7
  const int wm = w >> 2, wn = w & 3;   // 2 x 4 wave grid: 128 rows x 128 cols

  const unsigned bid = blockIdx.x;     // 0..511
  const int xcd  = bid & 7;
  const int s    = bid >> 3;           // 0..63
  const int mt   = s & 7;              // 8 m-tiles
  const int nt0  = xcd*256 + (s >> 3)*TPB;   // group walks nt0..nt0+31

  // prologue: copy A slab (frags rt=mt*4..+4 x kt=0..8 = 64KB contiguous)
  #pragma unroll
  for (int i=0; i<8; i++)
    __builtin_amdgcn_global_load_lds(
        (gbl_uchar*)(qp + (size_t)mt*65536u + tid*16 + i*8192),
        (lds_uchar*)(alds + tid*16 + i*8192), 16, 0, 0);
  __syncthreads();                      // the ONLY block-wide sync

  f32x16 acc0 = {0}, acc1 = {0};
  union frag8 { uint4 q[2]; i32x8 v; };

  // B fragment stream: frag (ct = ntc*4 + wn, kt); 2KB lane-major
  const uint8_t* bptr = kp + ((size_t)(nt0*4 + wn)*8)*2048 + (unsigned)lane*16u;
  uint4 pf0 = *(const uint4*)(bptr);
  uint4 pf1 = *(const uint4*)(bptr + 1024);

  const unsigned aoffA = (unsigned)(wm*16)*2048u + (unsigned)lane*16u; // mh=0 base

  // epilogue helper: by-reference (no f32x16 copy — R15 register lesson)
  #define EPILOG(accR_, mh_) do{                                                \
    const int rbase = mt*BM + wm*64 + (mh_)*32 + 4*(lane>>5);                    \
    _Pragma("unroll")                                                            \
    for (int qd=0; qd<4; qd++){                                                  \
      float v0=(accR_)[qd*4+0], v1=(accR_)[qd*4+1];                              \
      float v2=(accR_)[qd*4+2], v3=(accR_)[qd*4+3];                              \
      float mx = fmaxf(fmaxf(v0,v1), fmaxf(v2,v3));                              \
      if (mx > TAU_S){                                                           \
        _Pragma("unroll")                                                        \
        for (int jj=0; jj<4; jj++){                                              \
          float v = (accR_)[qd*4+jj];                                            \
          if (v > TAU_S){                                                        \
            int rowg = rbase + jj + 8*qd;                                        \
            int pos = atomicAdd(cnt + rowg, 1);                                  \
            if (pos < CAP)                                                       \
              cand[(size_t)rowg*CAP + pos] = make_float2(v, __int_as_float(colg)); \
          }                                                                      \
        }                                                                        \
      }                                                                          \
    }                                                                            \
  }while(0)

  for (int t=0; t<TPB; t++){
    #pragma unroll
    for (int k8=0; k8<8; k8++){
      // prefetch next fragment (next kt, or next nt-tile's kt=0)
      const bool last = (t == TPB-1) && (k8 == 7);
      const uint8_t* bnext = bptr + (k8 == 7 ? 25*2048 : 2048);
      uint4 nf0, nf1;
      if (!last){
        nf0 = *(const uint4*)(bnext);
        nf1 = *(const uint4*)(bnext + 1024);
      }
      // A fragments from static LDS (conflict-free: lane*16 sequential)
      frag8 fa0, fa1, fb;
      const unsigned ao = aoffA + (unsigned)k8*2048u;
      fa0.q[0] = *(const uint4*)(alds + ao);
      fa0.q[1] = *(const uint4*)(alds + ao + 1024u);
      fa1.q[0] = *(const uint4*)(alds + ao + 16384u);
      fa1.q[1] = *(const uint4*)(alds + ao + 16384u + 1024u);
      fb.q[0] = pf0; fb.q[1] = pf1;
      __builtin_amdgcn_s_setprio(1);
      acc0 = __builtin_amdgcn_mfma_scale_f32_32x32x64_f8f6f4(
                 fa0.v, fb.v, acc0, 0, 0, 0, SC1, 0, SC1);
      acc1 = __builtin_amdgcn_mfma_scale_f32_32x32x64_f8f6f4(
                 fa1.v, fb.v, acc1, 0, 0, 0, SC1, 0, SC1);
      __builtin_amdgcn_s_setprio(0);
      pf0 = nf0; pf1 = nf1;
      bptr = bnext;
    }

    // ---- per-nt-tile epilogue: threshold filter + rare atomic append ----
    {
      const int ntc  = nt0 + t;
      const int colg = ntc*BN + wn*32 + (lane&31);
      EPILOG(acc0, 0);
      EPILOG(acc1, 1);
      acc0 = (f32x16){0}; acc1 = (f32x16){0};   // reset for next nt-tile
    }
  }
  #undef EPILOG
}

// One block per query: exact rank-select top-64 from candidate list ->
// exact fp64 rescore -> exact top-8 (ties: lower index) -> outputs.
__global__ __launch_bounds__(256) void merge_rescore(const int* __restrict__ cnt,
                                                     const float2* __restrict__ cand,
                                                     const float* __restrict__ q,
                                                     const float* __restrict__ keys,
                                                     const float* __restrict__ values,
                                                     float* __restrict__ out){
  const int qi = blockIdx.x, tid = threadIdx.x;
  const int lane = tid & 63, w = tid >> 6;
  __shared__ __align__(16) float qrow[D_DIM];
  __shared__ __align__(16) float2 ent[CAP];
  __shared__ int    widx[RWIN];
  __shared__ double dsc[RWIN];
  __shared__ double wq[4];
  __shared__ int    fidx[8];
  __shared__ double fsc[8];

  // stage q row + fp64 ||q||^2
  float2 qv = ((const float2*)(q + (size_t)qi*D_DIM))[tid];
  qrow[tid*2] = qv.x; qrow[tid*2+1] = qv.y;
  double pq = (double)qv.x*qv.x + (double)qv.y*qv.y;
  #pragma unroll
  for (int off=32; off>0; off>>=1) pq += __shfl_xor(pq, off);
  if (lane == 0) wq[w] = pq;

  const int n = min(cnt[qi], CAP);
  for (int i = tid; i < n; i += 256) ent[i] = cand[(size_t)qi*CAP + i];
  if (tid < RWIN) widx[tid] = -1;
  __syncthreads();
  double qq = wq[0]+wq[1]+wq[2]+wq[3];

  // exact rank-select: rank under (score desc, col asc); ranks are unique.
  for (int e = tid; e < n; e += 256){
    float se = ent[e].x; int ce = __float_as_int(ent[e].y);
    int rank = 0;
    for (int jx = 0; jx < n; jx++){
      float sj = ent[jx].x; int cj = __float_as_int(ent[jx].y);
      rank += (sj > se) || (sj == se && cj < ce);
    }
    if (rank < RWIN) widx[rank] = ce;
  }
  __syncthreads();

  // exact fp64 rescore: 4 threads per candidate (64 x 4 = 256)
  const int g = tid >> 2, sub = tid & 3;
  const int ki = widx[g];
  const int kis = (ki < 0) ? 0 : ki;
  const float4* kr4 = (const float4*)(keys + (size_t)kis*D_DIM);
  const float4* qr4 = (const float4*)qrow;
  double da = 0.0, dk = 0.0;
  for (int i=0;i<32;i++){
    float4 kv  = kr4[sub*32+i];
    float4 qv4 = qr4[sub*32+i];
    da += (double)qv4.x*kv.x + (double)qv4.y*kv.y + (double)qv4.z*kv.z + (double)qv4.w*kv.w;
    dk += (double)kv.x*kv.x + (double)kv.y*kv.y + (double)kv.z*kv.z + (double)kv.w*kv.w;
  }
  da += __shfl_down(da, 2, 4); da += __shfl_down(da, 1, 4);
  dk += __shfl_down(dk, 2, 4); dk += __shfl_down(dk, 1, 4);
  if (sub == 0){
    double nq = fmax(sqrt(qq), 1e-12);
    double nk = fmax(sqrt(dk), 1e-12);
    dsc[g] = (ki < 0) ? -1e300 : da/(nq*nk);
  }
  __syncthreads();

  if (tid == 0){
    for (int s=0; s<8; s++){
      double bs = -1e301; int bi = 0; int bx = 0x7fffffff;
      for (int c=0; c<RWIN; c++){
        double v = dsc[c]; int ix = widx[c];
        if (v > bs || (v == bs && ix >= 0 && ix < bx)){ bs = v; bi = c; bx = ix; }
      }
      fsc[s] = bs; fidx[s] = (bx == 0x7fffffff) ? 0 : bx;
      dsc[bi] = -1e302;   // remove
    }
  }
  __syncthreads();

  float* out_sc  = out + (size_t)B_Q*K_TOP*V_DIM;
  float* out_idx = out_sc + (size_t)B_Q*K_TOP;
  if (tid < 8){
    out_sc [qi*K_TOP + tid] = (float)fsc[tid];
    out_idx[qi*K_TOP + tid] = (float)fidx[tid];
  }
  #pragma unroll
  for (int s=0; s<8; s++){
    const float2* vr = (const float2*)(values + (size_t)fidx[s]*V_DIM);
    float2* orow = (float2*)(out + ((size_t)qi*K_TOP + s)*V_DIM);
    orow[tid] = vr[tid];
  }
}

extern "C" void kernel_launch(void* const* d_in, const int* in_sizes, int n_in,
                              void* d_out, int out_size, void* d_ws, size_t ws_size,
                              hipStream_t stream){
  const float* q      = (const float*)d_in[0];
  const float* keys   = (const float*)d_in[1];
  const float* values = (const float*)d_in[2];
  unsigned char* ws = (unsigned char*)d_ws;
  uint8_t* qp = (uint8_t*)ws;                                   // 512 KB (fp8 frag-packed)
  uint8_t* kp = qp + (size_t)B_Q*D_DIM;                         // 128 MB (fp8 frag-packed)
  int*    cnt  = (int*)(ws + (size_t)(B_Q + C_K)*D_DIM);        // 4 KB
  float2* cand = (float2*)(ws + (size_t)(B_Q + C_K)*D_DIM + 8192); // 16 MB
  float* out = (float*)d_out;

  hipFuncSetAttribute((const void*)gemm_topk,
                      hipFuncAttributeMaxDynamicSharedMemorySize, 65536);

  pack_rows<<<dim3(B_Q/32), dim3(256), 0, stream>>>(q, qp, cnt, B_Q);
  pack_rows<<<dim3(C_K/32), dim3(256), 0, stream>>>(keys, kp, nullptr, 0);
  gemm_topk<<<dim3(512), dim3(512), 65536, stream>>>(qp, kp, cnt, cand);
  merge_rescore<<<dim3(B_Q), dim3(256), 0, stream>>>(cnt, cand, q, keys, values, out);
}